// Round 3
// baseline (2949.786 us; speedup 1.0000x reference)
//
#include <hip/hip_runtime.h>

#define NNODES 200000
#define NEDGES 6400000
#define NENT   2048
#define CH     8
#define HID    32
#define NCONV  8
#define BN_EPS 1e-5f

#define BSZ    512                                  // nodes per bucket
#define NBUCK  ((NNODES + BSZ - 1) / BSZ)           // 391
#define CHUNK  4096
#define NCHUNK ((NEDGES + CHUNK - 1) / CHUNK)       // 1563

// ---------------- phase A: per-chunk bucket histogram ----------------
__global__ __launch_bounds__(256) void k_chist(const int* __restrict__ dst, int* __restrict__ cnt, int E){
  __shared__ int hist[NBUCK];
  for(int t=threadIdx.x; t<NBUCK; t+=256) hist[t]=0;
  __syncthreads();
  int e0 = blockIdx.x*CHUNK;
  int n = min(CHUNK, E-e0);
  for(int i=threadIdx.x; i<n; i+=256) atomicAdd(&hist[dst[e0+i]>>9], 1);
  __syncthreads();
  for(int t=threadIdx.x; t<NBUCK; t+=256) cnt[(size_t)blockIdx.x*NBUCK + t] = hist[t];
}

// ---------------- phase B1: per-bucket exclusive scan over chunks ----------------
__global__ __launch_bounds__(256) void k_cscan(int* __restrict__ cnt, int* __restrict__ total){
  int b = blockIdx.x;
  __shared__ int sd[256];
  int carry = 0;
  for(int base=0; base<NCHUNK; base+=256){
    int c = base + threadIdx.x;
    int v = (c<NCHUNK) ? cnt[(size_t)c*NBUCK + b] : 0;
    sd[threadIdx.x] = v; __syncthreads();
    #pragma unroll
    for(int o=1; o<256; o<<=1){
      int x = (threadIdx.x>=o) ? sd[threadIdx.x-o] : 0;
      __syncthreads();
      sd[threadIdx.x] += x;
      __syncthreads();
    }
    if(c<NCHUNK) cnt[(size_t)c*NBUCK + b] = carry + sd[threadIdx.x] - v;  // exclusive
    carry += sd[255];
    __syncthreads();
  }
  if(threadIdx.x==0) total[b] = carry;
}

// ---------------- phase B2: bucket base scan ----------------
__global__ __launch_bounds__(512) void k_bscan(const int* __restrict__ total, int* __restrict__ bbase){
  __shared__ int sd[512];
  int t = threadIdx.x;
  int v = (t<NBUCK) ? total[t] : 0;
  sd[t] = v; __syncthreads();
  #pragma unroll
  for(int o=1; o<512; o<<=1){
    int x = (t>=o) ? sd[t-o] : 0;
    __syncthreads();
    sd[t] += x;
    __syncthreads();
  }
  if(t<NBUCK) bbase[t] = sd[t] - v;
  if(t==511) bbase[NBUCK] = sd[511];   // == NEDGES
}

// ---------------- phase C: LDS counting-sort scatter into binned ----------------
// packed edge = (dst_local<<18) | src   (src<2^18, dst_local<512)
__global__ __launch_bounds__(512) void k_bin(const int* __restrict__ src, const int* __restrict__ dst,
                                             const int* __restrict__ cnt, const int* __restrict__ bbase,
                                             unsigned int* __restrict__ binned, int E){
  __shared__ int hist[NBUCK], excl[NBUCK], cur[NBUCK], base[NBUCK];
  __shared__ unsigned int pin[CHUNK];
  __shared__ unsigned short bk_in[CHUNK];
  __shared__ unsigned int sorted[CHUNK];
  __shared__ unsigned short sbkt[CHUNK];
  __shared__ int sd[512];
  int c = blockIdx.x;
  int e0 = c*CHUNK, n = min(CHUNK, E-e0);
  for(int t=threadIdx.x; t<NBUCK; t+=512) hist[t]=0;
  __syncthreads();
  for(int i=threadIdx.x; i<n; i+=512){
    int s = src[e0+i], d = dst[e0+i];
    int b = d>>9;
    pin[i]   = ((unsigned)(d & (BSZ-1))<<18) | (unsigned)s;
    bk_in[i] = (unsigned short)b;
    atomicAdd(&hist[b], 1);
  }
  __syncthreads();
  int t = threadIdx.x;
  int hv = (t<NBUCK) ? hist[t] : 0;
  sd[t] = hv; __syncthreads();
  #pragma unroll
  for(int o=1; o<512; o<<=1){
    int x = (t>=o) ? sd[t-o] : 0;
    __syncthreads();
    sd[t] += x;
    __syncthreads();
  }
  if(t<NBUCK){
    int ex = sd[t] - hv;
    excl[t] = ex; cur[t] = ex;
    base[t] = bbase[t] + cnt[(size_t)c*NBUCK + t];
  }
  __syncthreads();
  for(int i=threadIdx.x; i<n; i+=512){
    int b = bk_in[i];
    int slot = atomicAdd(&cur[b], 1);
    sorted[slot] = pin[i];
    sbkt[slot]   = (unsigned short)b;
  }
  __syncthreads();
  for(int i=threadIdx.x; i<n; i+=512){
    int b = sbkt[i];
    binned[ base[b] + (i - excl[b]) ] = sorted[i];   // contiguous runs per bucket
  }
}

// ---------------- degree per bucket -> dinv ----------------
__global__ __launch_bounds__(512) void k_degb(const unsigned int* __restrict__ binned,
                                              const int* __restrict__ bbase,
                                              float* __restrict__ dinv, int N){
  __shared__ int hist[BSZ];
  int b = blockIdx.x, t = threadIdx.x;
  hist[t] = 0; __syncthreads();
  int s0 = bbase[b], s1 = bbase[b+1];
  for(int i=s0+t; i<s1; i+=512) atomicAdd(&hist[binned[i]>>18], 1);
  __syncthreads();
  int node = b*BSZ + t;
  if(node < N) dinv[node] = 1.0f / sqrtf((float)hist[t] + 1.0f);
}

// ---------------- h init: embedding gather + stats[0] ----------------
__global__ __launch_bounds__(256) void k_init_h(const int* __restrict__ x, const float* __restrict__ emb,
                                                float* __restrict__ h, double* __restrict__ stats0, int N){
  int i = blockIdx.x*256 + threadIdx.x;
  float v[CH];
  #pragma unroll
  for(int c=0;c<CH;c++) v[c]=0.f;
  if(i < N){
    int tt = x[i];
    const float4* ep = (const float4*)(emb + (size_t)tt*CH);
    float4 a = ep[0], b = ep[1];
    float4* hp = (float4*)(h + (size_t)i*CH);
    hp[0] = a; hp[1] = b;
    v[0]=a.x; v[1]=a.y; v[2]=a.z; v[3]=a.w; v[4]=b.x; v[5]=b.y; v[6]=b.z; v[7]=b.w;
  }
  float s[CH], q[CH];
  #pragma unroll
  for(int c=0;c<CH;c++){ s[c]=v[c]; q[c]=v[c]*v[c]; }
  #pragma unroll
  for(int off=32; off>0; off>>=1){
    #pragma unroll
    for(int c=0;c<CH;c++){ s[c]+=__shfl_down(s[c],off); q[c]+=__shfl_down(q[c],off); }
  }
  __shared__ float ls[4][2*CH];
  int wave = threadIdx.x>>6, lane = threadIdx.x&63;
  if(lane==0){
    #pragma unroll
    for(int c=0;c<CH;c++){ ls[wave][c]=s[c]; ls[wave][CH+c]=q[c]; }
  }
  __syncthreads();
  if(threadIdx.x < 2*CH){
    float tsum = ls[0][threadIdx.x]+ls[1][threadIdx.x]+ls[2][threadIdx.x]+ls[3][threadIdx.x];
    unsafeAtomicAdd(&stats0[threadIdx.x], (double)tsum);
  }
}

// ---------------- fold BN into 8x8 affine ----------------
__global__ void k_fold(const double* __restrict__ stats, const float* __restrict__ gamma,
                       const float* __restrict__ beta, const float* __restrict__ convw,
                       float* __restrict__ Af, int l){
  const double invN = 1.0 / (double)NNODES;
  float sarr[CH], tarr[CH];
  #pragma unroll
  for(int c=0;c<CH;c++){
    float mu  = (float)(stats[c]    * invN);
    float ex2 = (float)(stats[CH+c] * invN);
    float var = ex2 - mu*mu;
    float r   = 1.0f / sqrtf(var + BN_EPS);
    float sc  = r * gamma[l*CH+c];
    sarr[c] = sc;
    tarr[c] = beta[l*CH+c] - mu*sc;
  }
  int tid = threadIdx.x;
  if(tid < CH*CH){
    int ci = tid>>3, co = tid&7;
    Af[tid] = sarr[ci] * convw[(l*CH+ci)*CH+co];
  }
  if(tid < CH){
    float a = 0.f;
    #pragma unroll
    for(int ci=0;ci<CH;ci++) a += tarr[ci]*convw[(l*CH+ci)*CH+tid];
    Af[CH*CH+tid] = a;
  }
}

// ---------------- per-node transform: hts = (h@A + c0) * dinv ----------------
__global__ __launch_bounds__(256) void k_ht(const float* __restrict__ h, const float* __restrict__ Af,
                                            const float* __restrict__ dinv,
                                            float* __restrict__ hts, int N){
  __shared__ float A[CH*CH], c0[CH];
  if(threadIdx.x < CH*CH) A[threadIdx.x] = Af[threadIdx.x];
  if(threadIdx.x < CH) c0[threadIdx.x] = Af[CH*CH+threadIdx.x];
  __syncthreads();
  int i = blockIdx.x*blockDim.x + threadIdx.x;
  if(i >= N) return;
  const float4* hp = (const float4*)(h + (size_t)i*CH);
  float4 a = hp[0], b = hp[1];
  float v[CH] = {a.x,a.y,a.z,a.w,b.x,b.y,b.z,b.w};
  float o[CH];
  #pragma unroll
  for(int co=0;co<CH;co++) o[co]=c0[co];
  #pragma unroll
  for(int ci=0;ci<CH;ci++){
    float vv = v[ci];
    #pragma unroll
    for(int co=0;co<CH;co++) o[co] += vv*A[ci*CH+co];
  }
  float dn = dinv[i];
  float4* ho = (float4*)(hts + (size_t)i*CH);
  ho[0] = make_float4(o[0]*dn,o[1]*dn,o[2]*dn,o[3]*dn);
  ho[1] = make_float4(o[4]*dn,o[5]*dn,o[6]*dn,o[7]*dn);
}

// ---------------- bucket-local push aggregation + residual + ReLU + next stats ----------------
__global__ __launch_bounds__(512) void k_push(const unsigned int* __restrict__ binned,
                                              const int* __restrict__ bbase,
                                              const float* __restrict__ hts, const float* __restrict__ dinv,
                                              const float* __restrict__ convb,
                                              float* __restrict__ h, double* __restrict__ stats_next,
                                              int l, int N){
  __shared__ float acc[BSZ*CH];    // 16 KB
  int b = blockIdx.x, t = threadIdx.x;
  #pragma unroll
  for(int i=t; i<BSZ*CH; i+=512) acc[i] = 0.f;
  __syncthreads();
  int s0 = bbase[b], s1 = bbase[b+1];
  int lane8 = t & 7;
  for(int g = s0 + (t>>3); g < s1; g += 64){
    unsigned int p = binned[g];
    int srcn = p & 0x3FFFF;
    int dl   = p >> 18;
    float v = hts[(size_t)srcn*CH + lane8];
    atomicAdd(&acc[dl*CH + lane8], v);
  }
  __syncthreads();
  // epilogue: node per thread
  int node = b*BSZ + t;
  float vv[CH];
  #pragma unroll
  for(int c=0;c<CH;c++) vv[c]=0.f;
  if(node < N){
    const float4* hp  = (const float4*)(h   + (size_t)node*CH);
    const float4* hsp = (const float4*)(hts + (size_t)node*CH);
    float4 a = hp[0],  bb4 = hp[1];
    float4 sa = hsp[0], sb = hsp[1];
    float hv[CH] = {a.x,a.y,a.z,a.w,bb4.x,bb4.y,bb4.z,bb4.w};
    float hs[CH] = {sa.x,sa.y,sa.z,sa.w,sb.x,sb.y,sb.z,sb.w};
    const float4* ac = (const float4*)(acc + t*CH);
    float4 a0 = ac[0], a1 = ac[1];
    float av[CH] = {a0.x,a0.y,a0.z,a0.w,a1.x,a1.y,a1.z,a1.w};
    float dn = dinv[node];
    #pragma unroll
    for(int c=0;c<CH;c++){
      float r = hv[c] + convb[l*CH + c] + dn*(av[c] + hs[c]);
      vv[c] = fmaxf(r, 0.f);
    }
    float4* hw4 = (float4*)(h + (size_t)node*CH);
    hw4[0] = make_float4(vv[0],vv[1],vv[2],vv[3]);
    hw4[1] = make_float4(vv[4],vv[5],vv[6],vv[7]);
  }
  // next-layer BN stats
  float s[CH], q[CH];
  #pragma unroll
  for(int c=0;c<CH;c++){ s[c]=vv[c]; q[c]=vv[c]*vv[c]; }
  #pragma unroll
  for(int off=32; off>0; off>>=1){
    #pragma unroll
    for(int c=0;c<CH;c++){ s[c]+=__shfl_down(s[c],off); q[c]+=__shfl_down(q[c],off); }
  }
  __shared__ float ls[8][2*CH];
  int wave = t>>6, lane = t&63;
  if(lane==0){
    #pragma unroll
    for(int c=0;c<CH;c++){ ls[wave][c]=s[c]; ls[wave][CH+c]=q[c]; }
  }
  __syncthreads();
  if(t < 2*CH){
    float tsum = 0.f;
    #pragma unroll
    for(int w=0;w<8;w++) tsum += ls[w][t];
    unsafeAtomicAdd(&stats_next[t], (double)tsum);
  }
}

// ---------------- entries: u = xe@W1, v = xe@W2 + hb ----------------
__global__ __launch_bounds__(256) void k_uv(const int* __restrict__ entry, const float* __restrict__ h,
                                            const float* __restrict__ hw, const float* __restrict__ hb,
                                            float* __restrict__ u, float* __restrict__ v){
  __shared__ float w[2*CH*HID];
  __shared__ float b[HID];
  for(int t=threadIdx.x; t<2*CH*HID; t+=256) w[t]=hw[t];
  if(threadIdx.x<HID) b[threadIdx.x]=hb[threadIdx.x];
  __syncthreads();
  int k = blockIdx.x*blockDim.x + threadIdx.x;
  if(k >= NENT) return;
  int node = entry[k];
  const float4* hp = (const float4*)(h + (size_t)node*CH);
  float4 a = hp[0], b4 = hp[1];
  float xe[CH] = {a.x,a.y,a.z,a.w,b4.x,b4.y,b4.z,b4.w};
  #pragma unroll 4
  for(int c=0;c<HID;c++){
    float uu = 0.f, vv = b[c];
    #pragma unroll
    for(int ci=0;ci<CH;ci++){
      uu += xe[ci]*w[ci*HID+c];
      vv += xe[ci]*w[(CH+ci)*HID+c];
    }
    u[(size_t)k*HID+c] = uu;
    v[(size_t)k*HID+c] = vv;
  }
}

// ---------------- pairwise scorer ----------------
__global__ __launch_bounds__(256) void k_pair(const float* __restrict__ u, const float* __restrict__ v,
                                              const float* __restrict__ ow, const float* __restrict__ ob,
                                              float* __restrict__ out){
  __shared__ float us[16][HID+1];
  __shared__ float vs[64][HID+1];
  __shared__ float wo[HID];
  int tid = threadIdx.x;
  int jb = blockIdx.x*64, ib = blockIdx.y*16;
  for(int t=tid; t<16*HID; t+=256) us[t>>5][t&31] = u[(size_t)(ib + (t>>5))*HID + (t&31)];
  for(int t=tid; t<64*HID; t+=256) vs[t>>5][t&31] = v[(size_t)(jb + (t>>5))*HID + (t&31)];
  if(tid<HID) wo[tid]=ow[tid];
  __syncthreads();
  int tx = tid&63, ty = tid>>6;
  float a0=0.f, a1=0.f, a2=0.f, a3=0.f;
  #pragma unroll
  for(int c=0;c<HID;c++){
    float vv = vs[tx][c];
    float w  = wo[c];
    a0 += fmaxf(us[ty   ][c]+vv, 0.f)*w;
    a1 += fmaxf(us[ty+4 ][c]+vv, 0.f)*w;
    a2 += fmaxf(us[ty+8 ][c]+vv, 0.f)*w;
    a3 += fmaxf(us[ty+12][c]+vv, 0.f)*w;
  }
  float o0 = ob[0];
  size_t base = (size_t)ib*2048 + jb + tx;
  out[base + (size_t)(ty   )*2048] = a0+o0;
  out[base + (size_t)(ty+4 )*2048] = a1+o0;
  out[base + (size_t)(ty+8 )*2048] = a2+o0;
  out[base + (size_t)(ty+12)*2048] = a3+o0;
}

extern "C" void kernel_launch(void* const* d_in, const int* in_sizes, int n_in,
                              void* d_out, int out_size, void* d_ws, size_t ws_size,
                              hipStream_t stream){
  const int*   x     = (const int*)d_in[0];
  const int*   ei    = (const int*)d_in[1];
  const int*   entry = (const int*)d_in[2];
  const float* emb   = (const float*)d_in[3];
  const float* gamma = (const float*)d_in[4];
  const float* beta  = (const float*)d_in[5];
  const float* convw = (const float*)d_in[6];
  const float* convb = (const float*)d_in[7];
  const float* hw    = (const float*)d_in[8];
  const float* hb    = (const float*)d_in[9];
  const float* ow    = (const float*)d_in[10];
  const float* ob    = (const float*)d_in[11];
  const int* srcp = ei;
  const int* dstp = ei + NEDGES;

  // workspace (~42 MB)
  char* ws = (char*)d_ws;
  size_t o = 0;
  auto alloc = [&](size_t bytes){ void* p = ws + o; o += (bytes + 255) & ~(size_t)255; return p; };
  int*      cnt    = (int*)     alloc((size_t)NCHUNK*NBUCK*4);   // 2.44 MB
  int*      total  = (int*)     alloc(NBUCK*4);
  int*      bbase  = (int*)     alloc((NBUCK+1)*4);
  unsigned* binned = (unsigned*)alloc((size_t)NEDGES*4);         // 25.6 MB
  float*    dinv   = (float*)   alloc(NNODES*4);
  float*    h      = (float*)   alloc((size_t)NNODES*CH*4);
  float*    hts    = (float*)   alloc((size_t)NNODES*CH*4);
  double*   stats  = (double*)  alloc((NCONV+1)*2*CH*8);         // 9 slots of 16 doubles
  float*    Af     = (float*)   alloc((CH*CH+CH)*4);
  float*    ub     = (float*)   alloc((size_t)NENT*HID*4);
  float*    vb     = (float*)   alloc((size_t)NENT*HID*4);
  (void)ws_size; (void)in_sizes; (void)n_in; (void)out_size;

  // ---- deterministic CSR binning (no global atomics) ----
  k_chist<<<NCHUNK, 256, 0, stream>>>(dstp, cnt, NEDGES);
  k_cscan<<<NBUCK, 256, 0, stream>>>(cnt, total);
  k_bscan<<<1, 512, 0, stream>>>(total, bbase);
  k_bin  <<<NCHUNK, 512, 0, stream>>>(srcp, dstp, cnt, bbase, binned, NEDGES);
  k_degb <<<NBUCK, 512, 0, stream>>>(binned, bbase, dinv, NNODES);

  hipMemsetAsync(stats, 0, (NCONV+1)*2*CH*sizeof(double), stream);
  k_init_h<<<(NNODES+255)/256, 256, 0, stream>>>(x, emb, h, stats, NNODES);

  for(int l=0; l<NCONV; l++){
    k_fold<<<1, 64, 0, stream>>>(stats + (size_t)l*2*CH, gamma, beta, convw, Af, l);
    k_ht  <<<(NNODES+255)/256, 256, 0, stream>>>(h, Af, dinv, hts, NNODES);
    k_push<<<NBUCK, 512, 0, stream>>>(binned, bbase, hts, dinv, convb, h,
                                      stats + (size_t)(l+1)*2*CH, l, NNODES);
  }

  k_uv<<<NENT/256, 256, 0, stream>>>(entry, h, hw, hb, ub, vb);
  dim3 pg(2048/64, 2048/16);
  k_pair<<<pg, 256, 0, stream>>>(ub, vb, ow, ob, (float*)d_out);
}

// Round 4
// 920.733 us; speedup vs baseline: 3.2037x; 3.2037x over previous
//
#include <hip/hip_runtime.h>

#define NNODES 200000
#define NEDGES 6400000
#define NENT   2048
#define CH     8
#define HID    32
#define NCONV  8
#define BN_EPS 1e-5f

#define BSZ    512                                  // nodes per bucket
#define NBUCK  ((NNODES + BSZ - 1) / BSZ)           // 391
#define CHUNK  4096
#define NCHUNK ((NEDGES + CHUNK - 1) / CHUNK)       // 1563
#define NPB    2048                                 // k_pull blocks (partial-stats rows)

// ---------------- phase A: per-chunk bucket histogram ----------------
__global__ __launch_bounds__(256) void k_chist(const int* __restrict__ dst, int* __restrict__ cnt, int E){
  __shared__ int hist[NBUCK];
  for(int t=threadIdx.x; t<NBUCK; t+=256) hist[t]=0;
  __syncthreads();
  int e0 = blockIdx.x*CHUNK;
  int n = min(CHUNK, E-e0);
  for(int i=threadIdx.x; i<n; i+=256) atomicAdd(&hist[dst[e0+i]>>9], 1);
  __syncthreads();
  for(int t=threadIdx.x; t<NBUCK; t+=256) cnt[(size_t)blockIdx.x*NBUCK + t] = hist[t];
}

// ---------------- phase B1: per-bucket exclusive scan over chunks ----------------
__global__ __launch_bounds__(256) void k_cscan(int* __restrict__ cnt, int* __restrict__ total){
  int b = blockIdx.x;
  __shared__ int sd[256];
  int carry = 0;
  for(int base=0; base<NCHUNK; base+=256){
    int c = base + threadIdx.x;
    int v = (c<NCHUNK) ? cnt[(size_t)c*NBUCK + b] : 0;
    sd[threadIdx.x] = v; __syncthreads();
    #pragma unroll
    for(int o=1; o<256; o<<=1){
      int x = (threadIdx.x>=o) ? sd[threadIdx.x-o] : 0;
      __syncthreads();
      sd[threadIdx.x] += x;
      __syncthreads();
    }
    if(c<NCHUNK) cnt[(size_t)c*NBUCK + b] = carry + sd[threadIdx.x] - v;  // exclusive
    carry += sd[255];
    __syncthreads();
  }
  if(threadIdx.x==0) total[b] = carry;
}

// ---------------- phase B2: bucket base scan ----------------
__global__ __launch_bounds__(512) void k_bscan(const int* __restrict__ total, int* __restrict__ bbase){
  __shared__ int sd[512];
  int t = threadIdx.x;
  int v = (t<NBUCK) ? total[t] : 0;
  sd[t] = v; __syncthreads();
  #pragma unroll
  for(int o=1; o<512; o<<=1){
    int x = (t>=o) ? sd[t-o] : 0;
    __syncthreads();
    sd[t] += x;
    __syncthreads();
  }
  if(t<NBUCK) bbase[t] = sd[t] - v;
  if(t==511) bbase[NBUCK] = sd[511];   // == NEDGES
}

// ---------------- phase C: LDS counting-sort scatter into bucket runs ----------------
// packed edge = (dst_local<<18) | src   (src<2^18, dst_local<512)
__global__ __launch_bounds__(512) void k_bin(const int* __restrict__ src, const int* __restrict__ dst,
                                             const int* __restrict__ cnt, const int* __restrict__ bbase,
                                             unsigned int* __restrict__ binned, int E){
  __shared__ int hist[NBUCK], excl[NBUCK], cur[NBUCK], base[NBUCK];
  __shared__ unsigned int pin[CHUNK];
  __shared__ unsigned short bk_in[CHUNK];
  __shared__ unsigned int sorted[CHUNK];
  __shared__ unsigned short sbkt[CHUNK];
  __shared__ int sd[512];
  int c = blockIdx.x;
  int e0 = c*CHUNK, n = min(CHUNK, E-e0);
  for(int t=threadIdx.x; t<NBUCK; t+=512) hist[t]=0;
  __syncthreads();
  for(int i=threadIdx.x; i<n; i+=512){
    int s = src[e0+i], d = dst[e0+i];
    int b = d>>9;
    pin[i]   = ((unsigned)(d & (BSZ-1))<<18) | (unsigned)s;
    bk_in[i] = (unsigned short)b;
    atomicAdd(&hist[b], 1);
  }
  __syncthreads();
  int t = threadIdx.x;
  int hv = (t<NBUCK) ? hist[t] : 0;
  sd[t] = hv; __syncthreads();
  #pragma unroll
  for(int o=1; o<512; o<<=1){
    int x = (t>=o) ? sd[t-o] : 0;
    __syncthreads();
    sd[t] += x;
    __syncthreads();
  }
  if(t<NBUCK){
    int ex = sd[t] - hv;
    excl[t] = ex; cur[t] = ex;
    base[t] = bbase[t] + cnt[(size_t)c*NBUCK + t];
  }
  __syncthreads();
  for(int i=threadIdx.x; i<n; i+=512){
    int b = bk_in[i];
    int slot = atomicAdd(&cur[b], 1);
    sorted[slot] = pin[i];
    sbkt[slot]   = (unsigned short)b;
  }
  __syncthreads();
  for(int i=threadIdx.x; i<n; i+=512){
    int b = sbkt[i];
    binned[ base[b] + (i - excl[b]) ] = sorted[i];   // contiguous runs per bucket
  }
}

// ---------------- phase D: per-bucket counting sort -> full CSR + deg/dinv/csr_off ----------------
__global__ __launch_bounds__(512) void k_sub(const unsigned int* __restrict__ binned,
                                             const int* __restrict__ bbase,
                                             int* __restrict__ csrc, int* __restrict__ csr_off,
                                             float* __restrict__ dinv, int N){
  __shared__ int hist[BSZ], cur[BSZ], sd[BSZ];
  int b = blockIdx.x, t = threadIdx.x;
  hist[t] = 0;
  __syncthreads();
  int s0 = bbase[b], s1 = bbase[b+1];
  for(int i=s0+t; i<s1; i+=512) atomicAdd(&hist[binned[i]>>18], 1);
  __syncthreads();
  int hv = hist[t];
  sd[t] = hv; __syncthreads();
  #pragma unroll
  for(int o=1; o<512; o<<=1){
    int x = (t>=o) ? sd[t-o] : 0;
    __syncthreads();
    sd[t] += x;
    __syncthreads();
  }
  int ex = sd[t] - hv;
  cur[t] = ex;
  int node = b*BSZ + t;
  if(node < N){
    dinv[node]    = 1.0f / sqrtf((float)hv + 1.0f);
    csr_off[node] = s0 + ex;
  }
  if(b == NBUCK-1 && t == 511) csr_off[N] = s1;   // NEDGES
  __syncthreads();
  for(int i=s0+t; i<s1; i+=512){
    unsigned int p = binned[i];
    int dl = p>>18, sn = p & 0x3FFFF;
    int slot = atomicAdd(&cur[dl], 1);
    csrc[s0 + slot] = sn;
  }
}

// ---------------- h init: embedding gather + stats[0] ----------------
__global__ __launch_bounds__(256) void k_init_h(const int* __restrict__ x, const float* __restrict__ emb,
                                                float* __restrict__ h, double* __restrict__ stats0, int N){
  int i = blockIdx.x*256 + threadIdx.x;
  float v[CH];
  #pragma unroll
  for(int c=0;c<CH;c++) v[c]=0.f;
  if(i < N){
    int tt = x[i];
    const float4* ep = (const float4*)(emb + (size_t)tt*CH);
    float4 a = ep[0], b = ep[1];
    float4* hp = (float4*)(h + (size_t)i*CH);
    hp[0] = a; hp[1] = b;
    v[0]=a.x; v[1]=a.y; v[2]=a.z; v[3]=a.w; v[4]=b.x; v[5]=b.y; v[6]=b.z; v[7]=b.w;
  }
  float s[CH], q[CH];
  #pragma unroll
  for(int c=0;c<CH;c++){ s[c]=v[c]; q[c]=v[c]*v[c]; }
  #pragma unroll
  for(int off=32; off>0; off>>=1){
    #pragma unroll
    for(int c=0;c<CH;c++){ s[c]+=__shfl_down(s[c],off); q[c]+=__shfl_down(q[c],off); }
  }
  __shared__ float ls[4][2*CH];
  int wave = threadIdx.x>>6, lane = threadIdx.x&63;
  if(lane==0){
    #pragma unroll
    for(int c=0;c<CH;c++){ ls[wave][c]=s[c]; ls[wave][CH+c]=q[c]; }
  }
  __syncthreads();
  if(threadIdx.x < 2*CH){
    float tsum = ls[0][threadIdx.x]+ls[1][threadIdx.x]+ls[2][threadIdx.x]+ls[3][threadIdx.x];
    unsafeAtomicAdd(&stats0[threadIdx.x], (double)tsum);
  }
}

// ---------------- fold: reduce stats (slot or partials) + build 8x8 affine ----------------
__global__ __launch_bounds__(512) void k_fold(const double* __restrict__ stats0,
                                              const float* __restrict__ part, int use_part,
                                              const float* __restrict__ gamma, const float* __restrict__ beta,
                                              const float* __restrict__ convw, float* __restrict__ Af, int l){
  __shared__ float red[32][17];
  __shared__ double tot[2*CH];
  __shared__ float sarr[CH], tarr[CH];
  int t = threadIdx.x;
  if(use_part){
    int col = t & 15, g = t >> 4;
    float acc = 0.f;
    for(int r=g; r<NPB; r+=32) acc += part[(size_t)r*16 + col];
    red[g][col] = acc;
    __syncthreads();
    if(t < 16){
      double d = 0.0;
      #pragma unroll
      for(int g2=0; g2<32; g2++) d += (double)red[g2][t];
      tot[t] = d;
    }
  } else {
    if(t < 16) tot[t] = stats0[t];
  }
  __syncthreads();
  if(t < CH){
    const double invN = 1.0 / (double)NNODES;
    float mu  = (float)(tot[t]    * invN);
    float ex2 = (float)(tot[CH+t] * invN);
    float var = ex2 - mu*mu;
    float r   = 1.0f / sqrtf(var + BN_EPS);
    float sc  = r * gamma[l*CH+t];
    sarr[t] = sc;
    tarr[t] = beta[l*CH+t] - mu*sc;
  }
  __syncthreads();
  if(t < CH*CH){
    int ci = t>>3, co = t&7;
    Af[t] = sarr[ci] * convw[(l*CH+ci)*CH+co];
  }
  if(t < CH){
    float a = 0.f;
    #pragma unroll
    for(int ci=0;ci<CH;ci++) a += tarr[ci]*convw[(l*CH+ci)*CH+t];
    Af[CH*CH+t] = a;
  }
}

// ---------------- per-node transform: hts = (h@A + c0) * dinv ----------------
__global__ __launch_bounds__(256) void k_ht(const float* __restrict__ h, const float* __restrict__ Af,
                                            const float* __restrict__ dinv,
                                            float* __restrict__ hts, int N){
  __shared__ float A[CH*CH], c0[CH];
  if(threadIdx.x < CH*CH) A[threadIdx.x] = Af[threadIdx.x];
  if(threadIdx.x < CH) c0[threadIdx.x] = Af[CH*CH+threadIdx.x];
  __syncthreads();
  int i = blockIdx.x*blockDim.x + threadIdx.x;
  if(i >= N) return;
  const float4* hp = (const float4*)(h + (size_t)i*CH);
  float4 a = hp[0], b = hp[1];
  float v[CH] = {a.x,a.y,a.z,a.w,b.x,b.y,b.z,b.w};
  float o[CH];
  #pragma unroll
  for(int co=0;co<CH;co++) o[co]=c0[co];
  #pragma unroll
  for(int ci=0;ci<CH;ci++){
    float vv = v[ci];
    #pragma unroll
    for(int co=0;co<CH;co++) o[co] += vv*A[ci*CH+co];
  }
  float dn = dinv[i];
  float4* ho = (float4*)(hts + (size_t)i*CH);
  ho[0] = make_float4(o[0]*dn,o[1]*dn,o[2]*dn,o[3]*dn);
  ho[1] = make_float4(o[4]*dn,o[5]*dn,o[6]*dn,o[7]*dn);
}

// ---------------- pull aggregation + residual + ReLU + next-layer stats partials ----------------
// 8 lanes per node; grid-stride over node-groups; no atomics.
__global__ __launch_bounds__(256) void k_pull(const int* __restrict__ off, const int* __restrict__ csrc,
                                              const float* __restrict__ hts, const float* __restrict__ dinv,
                                              const float* __restrict__ convb,
                                              float* __restrict__ h, float* __restrict__ part,
                                              int l, int N){
  int lane8 = threadIdx.x & 7;
  float S = 0.f, Q = 0.f;
  for(int tid = blockIdx.x*256 + threadIdx.x; tid < N*CH; tid += NPB*256){
    int node = tid >> 3;
    int s0 = off[node], s1 = off[node+1];
    float sum = hts[(size_t)node*CH + lane8];      // self loop (premultiplied by dinv[node])
    int e = s0;
    for(; e + 4 <= s1; e += 4){
      int sa = csrc[e], sb = csrc[e+1], sc = csrc[e+2], sd = csrc[e+3];
      sum += hts[(size_t)sa*CH + lane8] + hts[(size_t)sb*CH + lane8]
           + hts[(size_t)sc*CH + lane8] + hts[(size_t)sd*CH + lane8];
    }
    for(; e < s1; e++) sum += hts[(size_t)csrc[e]*CH + lane8];
    float r = h[(size_t)node*CH + lane8] + convb[l*CH + lane8] + dinv[node]*sum;
    float val = fmaxf(r, 0.f);
    h[(size_t)node*CH + lane8] = val;
    S += val; Q += val*val;
  }
  // reduce stats within wave: combine the 8 node-slots per wave (xor 8,16,32)
  S += __shfl_xor(S, 8);  Q += __shfl_xor(Q, 8);
  S += __shfl_xor(S, 16); Q += __shfl_xor(Q, 16);
  S += __shfl_xor(S, 32); Q += __shfl_xor(Q, 32);
  __shared__ float ls[4][2*CH];
  int wave = threadIdx.x>>6, wl = threadIdx.x&63;
  if(wl < CH){ ls[wave][wl] = S; ls[wave][CH+wl] = Q; }
  __syncthreads();
  if(threadIdx.x < 2*CH){
    float tsum = ls[0][threadIdx.x]+ls[1][threadIdx.x]+ls[2][threadIdx.x]+ls[3][threadIdx.x];
    part[(size_t)blockIdx.x*16 + threadIdx.x] = tsum;
  }
}

// ---------------- entries: u = xe@W1, v = xe@W2 + hb ----------------
__global__ __launch_bounds__(256) void k_uv(const int* __restrict__ entry, const float* __restrict__ h,
                                            const float* __restrict__ hw, const float* __restrict__ hb,
                                            float* __restrict__ u, float* __restrict__ v){
  __shared__ float w[2*CH*HID];
  __shared__ float b[HID];
  for(int t=threadIdx.x; t<2*CH*HID; t+=256) w[t]=hw[t];
  if(threadIdx.x<HID) b[threadIdx.x]=hb[threadIdx.x];
  __syncthreads();
  int k = blockIdx.x*blockDim.x + threadIdx.x;
  if(k >= NENT) return;
  int node = entry[k];
  const float4* hp = (const float4*)(h + (size_t)node*CH);
  float4 a = hp[0], b4 = hp[1];
  float xe[CH] = {a.x,a.y,a.z,a.w,b4.x,b4.y,b4.z,b4.w};
  #pragma unroll 4
  for(int c=0;c<HID;c++){
    float uu = 0.f, vv = b[c];
    #pragma unroll
    for(int ci=0;ci<CH;ci++){
      uu += xe[ci]*w[ci*HID+c];
      vv += xe[ci]*w[(CH+ci)*HID+c];
    }
    u[(size_t)k*HID+c] = uu;
    v[(size_t)k*HID+c] = vv;
  }
}

// ---------------- pairwise scorer ----------------
__global__ __launch_bounds__(256) void k_pair(const float* __restrict__ u, const float* __restrict__ v,
                                              const float* __restrict__ ow, const float* __restrict__ ob,
                                              float* __restrict__ out){
  __shared__ float us[16][HID+1];
  __shared__ float vs[64][HID+1];
  __shared__ float wo[HID];
  int tid = threadIdx.x;
  int jb = blockIdx.x*64, ib = blockIdx.y*16;
  for(int t=tid; t<16*HID; t+=256) us[t>>5][t&31] = u[(size_t)(ib + (t>>5))*HID + (t&31)];
  for(int t=tid; t<64*HID; t+=256) vs[t>>5][t&31] = v[(size_t)(jb + (t>>5))*HID + (t&31)];
  if(tid<HID) wo[tid]=ow[tid];
  __syncthreads();
  int tx = tid&63, ty = tid>>6;
  float a0=0.f, a1=0.f, a2=0.f, a3=0.f;
  #pragma unroll
  for(int c=0;c<HID;c++){
    float vv = vs[tx][c];
    float w  = wo[c];
    a0 += fmaxf(us[ty   ][c]+vv, 0.f)*w;
    a1 += fmaxf(us[ty+4 ][c]+vv, 0.f)*w;
    a2 += fmaxf(us[ty+8 ][c]+vv, 0.f)*w;
    a3 += fmaxf(us[ty+12][c]+vv, 0.f)*w;
  }
  float o0 = ob[0];
  size_t base = (size_t)ib*2048 + jb + tx;
  out[base + (size_t)(ty   )*2048] = a0+o0;
  out[base + (size_t)(ty+4 )*2048] = a1+o0;
  out[base + (size_t)(ty+8 )*2048] = a2+o0;
  out[base + (size_t)(ty+12)*2048] = a3+o0;
}

extern "C" void kernel_launch(void* const* d_in, const int* in_sizes, int n_in,
                              void* d_out, int out_size, void* d_ws, size_t ws_size,
                              hipStream_t stream){
  const int*   x     = (const int*)d_in[0];
  const int*   ei    = (const int*)d_in[1];
  const int*   entry = (const int*)d_in[2];
  const float* emb   = (const float*)d_in[3];
  const float* gamma = (const float*)d_in[4];
  const float* beta  = (const float*)d_in[5];
  const float* convw = (const float*)d_in[6];
  const float* convb = (const float*)d_in[7];
  const float* hw    = (const float*)d_in[8];
  const float* hb    = (const float*)d_in[9];
  const float* ow    = (const float*)d_in[10];
  const float* ob    = (const float*)d_in[11];
  const int* srcp = ei;
  const int* dstp = ei + NEDGES;

  // workspace (~70 MB)
  char* ws = (char*)d_ws;
  size_t o = 0;
  auto alloc = [&](size_t bytes){ void* p = ws + o; o += (bytes + 255) & ~(size_t)255; return p; };
  int*      cnt    = (int*)     alloc((size_t)NCHUNK*NBUCK*4);   // 2.44 MB
  int*      total  = (int*)     alloc(NBUCK*4);
  int*      bbase  = (int*)     alloc((NBUCK+1)*4);
  unsigned* binned = (unsigned*)alloc((size_t)NEDGES*4);         // 25.6 MB
  int*      csrc   = (int*)     alloc((size_t)NEDGES*4);         // 25.6 MB
  int*      csr_off= (int*)     alloc((NNODES+1)*4);
  float*    dinv   = (float*)   alloc(NNODES*4);
  float*    h      = (float*)   alloc((size_t)NNODES*CH*4);
  float*    hts    = (float*)   alloc((size_t)NNODES*CH*4);
  double*   stats0 = (double*)  alloc(2*CH*8);
  float*    part   = (float*)   alloc((size_t)NPB*16*4);         // 128 KB
  float*    Af     = (float*)   alloc((CH*CH+CH)*4);
  float*    ub     = (float*)   alloc((size_t)NENT*HID*4);
  float*    vb     = (float*)   alloc((size_t)NENT*HID*4);
  (void)ws_size; (void)in_sizes; (void)n_in; (void)out_size;

  // ---- deterministic CSR build (no global atomics) ----
  k_chist<<<NCHUNK, 256, 0, stream>>>(dstp, cnt, NEDGES);
  k_cscan<<<NBUCK, 256, 0, stream>>>(cnt, total);
  k_bscan<<<1, 512, 0, stream>>>(total, bbase);
  k_bin  <<<NCHUNK, 512, 0, stream>>>(srcp, dstp, cnt, bbase, binned, NEDGES);
  k_sub  <<<NBUCK, 512, 0, stream>>>(binned, bbase, csrc, csr_off, dinv, NNODES);

  hipMemsetAsync(stats0, 0, 2*CH*sizeof(double), stream);
  k_init_h<<<(NNODES+255)/256, 256, 0, stream>>>(x, emb, h, stats0, NNODES);

  for(int l=0; l<NCONV; l++){
    k_fold<<<1, 512, 0, stream>>>(stats0, part, (l>0)?1:0, gamma, beta, convw, Af, l);
    k_ht  <<<(NNODES+255)/256, 256, 0, stream>>>(h, Af, dinv, hts, NNODES);
    k_pull<<<NPB, 256, 0, stream>>>(csr_off, csrc, hts, dinv, convb, h, part, l, NNODES);
  }

  k_uv<<<NENT/256, 256, 0, stream>>>(entry, h, hw, hb, ub, vb);
  dim3 pg(2048/64, 2048/16);
  k_pair<<<pg, 256, 0, stream>>>(ub, vb, ow, ob, (float*)d_out);
}

// Round 5
// 711.197 us; speedup vs baseline: 4.1476x; 1.2946x over previous
//
#include <hip/hip_runtime.h>
#include <hip/hip_fp16.h>

#define NNODES 200000
#define NEDGES 6400000
#define NENT   2048
#define CH     8
#define HID    32
#define NCONV  8
#define BN_EPS 1e-5f

#define BSZ    512                                  // nodes per bucket
#define NBUCK  ((NNODES + BSZ - 1) / BSZ)           // 391
#define CHUNK  4096
#define NCHUNK ((NEDGES + CHUNK - 1) / CHUNK)       // 1563
#define NPB    2048                                 // k_pull blocks (partial-stats rows)

// ---------------- phase A: per-chunk bucket histogram ----------------
__global__ __launch_bounds__(256) void k_chist(const int* __restrict__ dst, int* __restrict__ cnt, int E){
  __shared__ int hist[NBUCK];
  for(int t=threadIdx.x; t<NBUCK; t+=256) hist[t]=0;
  __syncthreads();
  int e0 = blockIdx.x*CHUNK;
  int n = min(CHUNK, E-e0);
  for(int i=threadIdx.x; i<n; i+=256) atomicAdd(&hist[dst[e0+i]>>9], 1);
  __syncthreads();
  for(int t=threadIdx.x; t<NBUCK; t+=256) cnt[(size_t)blockIdx.x*NBUCK + t] = hist[t];
}

// ---------------- phase B1: per-bucket exclusive scan over chunks ----------------
__global__ __launch_bounds__(256) void k_cscan(int* __restrict__ cnt, int* __restrict__ total){
  int b = blockIdx.x;
  __shared__ int sd[256];
  int carry = 0;
  for(int base=0; base<NCHUNK; base+=256){
    int c = base + threadIdx.x;
    int v = (c<NCHUNK) ? cnt[(size_t)c*NBUCK + b] : 0;
    sd[threadIdx.x] = v; __syncthreads();
    #pragma unroll
    for(int o=1; o<256; o<<=1){
      int x = (threadIdx.x>=o) ? sd[threadIdx.x-o] : 0;
      __syncthreads();
      sd[threadIdx.x] += x;
      __syncthreads();
    }
    if(c<NCHUNK) cnt[(size_t)c*NBUCK + b] = carry + sd[threadIdx.x] - v;  // exclusive
    carry += sd[255];
    __syncthreads();
  }
  if(threadIdx.x==0) total[b] = carry;
}

// ---------------- phase B2: bucket base scan ----------------
__global__ __launch_bounds__(512) void k_bscan(const int* __restrict__ total, int* __restrict__ bbase){
  __shared__ int sd[512];
  int t = threadIdx.x;
  int v = (t<NBUCK) ? total[t] : 0;
  sd[t] = v; __syncthreads();
  #pragma unroll
  for(int o=1; o<512; o<<=1){
    int x = (t>=o) ? sd[t-o] : 0;
    __syncthreads();
    sd[t] += x;
    __syncthreads();
  }
  if(t<NBUCK) bbase[t] = sd[t] - v;
  if(t==511) bbase[NBUCK] = sd[511];   // == NEDGES
}

// ---------------- phase C: LDS counting-sort scatter into bucket runs ----------------
// packed edge = (dst_local<<18) | src   (src<2^18, dst_local<512)
__global__ __launch_bounds__(512) void k_bin(const int* __restrict__ src, const int* __restrict__ dst,
                                             const int* __restrict__ cnt, const int* __restrict__ bbase,
                                             unsigned int* __restrict__ binned, int E){
  __shared__ int hist[NBUCK], excl[NBUCK], cur[NBUCK], base[NBUCK];
  __shared__ unsigned int pin[CHUNK];
  __shared__ unsigned short bk_in[CHUNK];
  __shared__ unsigned int sorted[CHUNK];
  __shared__ unsigned short sbkt[CHUNK];
  __shared__ int sd[512];
  int c = blockIdx.x;
  int e0 = c*CHUNK, n = min(CHUNK, E-e0);
  for(int t=threadIdx.x; t<NBUCK; t+=512) hist[t]=0;
  __syncthreads();
  for(int i=threadIdx.x; i<n; i+=512){
    int s = src[e0+i], d = dst[e0+i];
    int b = d>>9;
    pin[i]   = ((unsigned)(d & (BSZ-1))<<18) | (unsigned)s;
    bk_in[i] = (unsigned short)b;
    atomicAdd(&hist[b], 1);
  }
  __syncthreads();
  int t = threadIdx.x;
  int hv = (t<NBUCK) ? hist[t] : 0;
  sd[t] = hv; __syncthreads();
  #pragma unroll
  for(int o=1; o<512; o<<=1){
    int x = (t>=o) ? sd[t-o] : 0;
    __syncthreads();
    sd[t] += x;
    __syncthreads();
  }
  if(t<NBUCK){
    int ex = sd[t] - hv;
    excl[t] = ex; cur[t] = ex;
    base[t] = bbase[t] + cnt[(size_t)c*NBUCK + t];
  }
  __syncthreads();
  for(int i=threadIdx.x; i<n; i+=512){
    int b = bk_in[i];
    int slot = atomicAdd(&cur[b], 1);
    sorted[slot] = pin[i];
    sbkt[slot]   = (unsigned short)b;
  }
  __syncthreads();
  for(int i=threadIdx.x; i<n; i+=512){
    int b = sbkt[i];
    binned[ base[b] + (i - excl[b]) ] = sorted[i];   // contiguous runs per bucket
  }
}

// ---------------- phase D: per-bucket counting sort -> full CSR + deg/dinv/csr_off ----------------
__global__ __launch_bounds__(512) void k_sub(const unsigned int* __restrict__ binned,
                                             const int* __restrict__ bbase,
                                             int* __restrict__ csrc, int* __restrict__ csr_off,
                                             float* __restrict__ dinv, int N){
  __shared__ int hist[BSZ], cur[BSZ], sd[BSZ];
  int b = blockIdx.x, t = threadIdx.x;
  hist[t] = 0;
  __syncthreads();
  int s0 = bbase[b], s1 = bbase[b+1];
  for(int i=s0+t; i<s1; i+=512) atomicAdd(&hist[binned[i]>>18], 1);
  __syncthreads();
  int hv = hist[t];
  sd[t] = hv; __syncthreads();
  #pragma unroll
  for(int o=1; o<512; o<<=1){
    int x = (t>=o) ? sd[t-o] : 0;
    __syncthreads();
    sd[t] += x;
    __syncthreads();
  }
  int ex = sd[t] - hv;
  cur[t] = ex;
  int node = b*BSZ + t;
  if(node < N){
    dinv[node]    = 1.0f / sqrtf((float)hv + 1.0f);
    csr_off[node] = s0 + ex;
  }
  if(b == NBUCK-1 && t == 511) csr_off[N] = s1;   // NEDGES
  __syncthreads();
  for(int i=s0+t; i<s1; i+=512){
    unsigned int p = binned[i];
    int dl = p>>18, sn = p & 0x3FFFF;
    int slot = atomicAdd(&cur[dl], 1);
    csrc[s0 + slot] = sn;
  }
}

// ---------------- h init: embedding gather + stats[0] ----------------
__global__ __launch_bounds__(256) void k_init_h(const int* __restrict__ x, const float* __restrict__ emb,
                                                float* __restrict__ h, double* __restrict__ stats0, int N){
  int i = blockIdx.x*256 + threadIdx.x;
  float v[CH];
  #pragma unroll
  for(int c=0;c<CH;c++) v[c]=0.f;
  if(i < N){
    int tt = x[i];
    const float4* ep = (const float4*)(emb + (size_t)tt*CH);
    float4 a = ep[0], b = ep[1];
    float4* hp = (float4*)(h + (size_t)i*CH);
    hp[0] = a; hp[1] = b;
    v[0]=a.x; v[1]=a.y; v[2]=a.z; v[3]=a.w; v[4]=b.x; v[5]=b.y; v[6]=b.z; v[7]=b.w;
  }
  float s[CH], q[CH];
  #pragma unroll
  for(int c=0;c<CH;c++){ s[c]=v[c]; q[c]=v[c]*v[c]; }
  #pragma unroll
  for(int off=32; off>0; off>>=1){
    #pragma unroll
    for(int c=0;c<CH;c++){ s[c]+=__shfl_down(s[c],off); q[c]+=__shfl_down(q[c],off); }
  }
  __shared__ float ls[4][2*CH];
  int wave = threadIdx.x>>6, lane = threadIdx.x&63;
  if(lane==0){
    #pragma unroll
    for(int c=0;c<CH;c++){ ls[wave][c]=s[c]; ls[wave][CH+c]=q[c]; }
  }
  __syncthreads();
  if(threadIdx.x < 2*CH){
    float tsum = ls[0][threadIdx.x]+ls[1][threadIdx.x]+ls[2][threadIdx.x]+ls[3][threadIdx.x];
    unsafeAtomicAdd(&stats0[threadIdx.x], (double)tsum);
  }
}

// ---------------- fold: reduce stats (slot or partials) + build 8x8 affine ----------------
__global__ __launch_bounds__(512) void k_fold(const double* __restrict__ stats0,
                                              const float* __restrict__ part, int use_part,
                                              const float* __restrict__ gamma, const float* __restrict__ beta,
                                              const float* __restrict__ convw, float* __restrict__ Af, int l){
  __shared__ float red[32][17];
  __shared__ double tot[2*CH];
  __shared__ float sarr[CH], tarr[CH];
  int t = threadIdx.x;
  if(use_part){
    int col = t & 15, g = t >> 4;
    float acc = 0.f;
    for(int r=g; r<NPB; r+=32) acc += part[(size_t)r*16 + col];
    red[g][col] = acc;
    __syncthreads();
    if(t < 16){
      double d = 0.0;
      #pragma unroll
      for(int g2=0; g2<32; g2++) d += (double)red[g2][t];
      tot[t] = d;
    }
  } else {
    if(t < 16) tot[t] = stats0[t];
  }
  __syncthreads();
  if(t < CH){
    const double invN = 1.0 / (double)NNODES;
    float mu  = (float)(tot[t]    * invN);
    float ex2 = (float)(tot[CH+t] * invN);
    float var = ex2 - mu*mu;
    float r   = 1.0f / sqrtf(var + BN_EPS);
    float sc  = r * gamma[l*CH+t];
    sarr[t] = sc;
    tarr[t] = beta[l*CH+t] - mu*sc;
  }
  __syncthreads();
  if(t < CH*CH){
    int ci = t>>3, co = t&7;
    Af[t] = sarr[ci] * convw[(l*CH+ci)*CH+co];
  }
  if(t < CH){
    float a = 0.f;
    #pragma unroll
    for(int ci=0;ci<CH;ci++) a += tarr[ci]*convw[(l*CH+ci)*CH+t];
    Af[CH*CH+t] = a;
  }
}

// ---------------- per-node transform: hts16 = fp16( (h@A + c0) * dinv ) ----------------
__global__ __launch_bounds__(256) void k_ht(const float* __restrict__ h, const float* __restrict__ Af,
                                            const float* __restrict__ dinv,
                                            __half* __restrict__ hts16, int N){
  __shared__ float A[CH*CH], c0[CH];
  if(threadIdx.x < CH*CH) A[threadIdx.x] = Af[threadIdx.x];
  if(threadIdx.x < CH) c0[threadIdx.x] = Af[CH*CH+threadIdx.x];
  __syncthreads();
  int i = blockIdx.x*blockDim.x + threadIdx.x;
  if(i >= N) return;
  const float4* hp = (const float4*)(h + (size_t)i*CH);
  float4 a = hp[0], b = hp[1];
  float v[CH] = {a.x,a.y,a.z,a.w,b.x,b.y,b.z,b.w};
  float o[CH];
  #pragma unroll
  for(int co=0;co<CH;co++) o[co]=c0[co];
  #pragma unroll
  for(int ci=0;ci<CH;ci++){
    float vv = v[ci];
    #pragma unroll
    for(int co=0;co<CH;co++) o[co] += vv*A[ci*CH+co];
  }
  float dn = dinv[i];
  union { __half hh[CH]; uint4 u; } pk;
  #pragma unroll
  for(int c=0;c<CH;c++) pk.hh[c] = __float2half(o[c]*dn);
  *(uint4*)(hts16 + (size_t)i*CH) = pk.u;
}

// ---------------- pull aggregation + residual + ReLU + next-layer stats partials ----------------
// 8 lanes per node; grid-stride; fp16 hts (3.2 MB -> per-XCD L2 resident); no atomics.
__global__ __launch_bounds__(256) void k_pull(const int* __restrict__ off, const int* __restrict__ csrc,
                                              const __half* __restrict__ hts16, const float* __restrict__ dinv,
                                              const float* __restrict__ convb,
                                              float* __restrict__ h, float* __restrict__ part,
                                              int l, int N){
  int lane8 = threadIdx.x & 7;
  float S = 0.f, Q = 0.f;
  for(int tid = blockIdx.x*256 + threadIdx.x; tid < N*CH; tid += NPB*256){
    int node = tid >> 3;
    int s0 = off[node], s1 = off[node+1];
    float sum = __half2float(hts16[(size_t)node*CH + lane8]);   // self loop (pre-scaled by dinv[node])
    int e = s0;
    for(; e + 4 <= s1; e += 4){
      int sa = csrc[e], sb = csrc[e+1], sc = csrc[e+2], sd = csrc[e+3];
      float va = __half2float(hts16[(size_t)sa*CH + lane8]);
      float vb = __half2float(hts16[(size_t)sb*CH + lane8]);
      float vc = __half2float(hts16[(size_t)sc*CH + lane8]);
      float vd = __half2float(hts16[(size_t)sd*CH + lane8]);
      sum += va + vb + vc + vd;
    }
    for(; e < s1; e++) sum += __half2float(hts16[(size_t)csrc[e]*CH + lane8]);
    float r = h[(size_t)node*CH + lane8] + convb[l*CH + lane8] + dinv[node]*sum;
    float val = fmaxf(r, 0.f);
    h[(size_t)node*CH + lane8] = val;
    S += val; Q += val*val;
  }
  // reduce stats within wave: combine the 8 node-slots per wave (xor 8,16,32)
  S += __shfl_xor(S, 8);  Q += __shfl_xor(Q, 8);
  S += __shfl_xor(S, 16); Q += __shfl_xor(Q, 16);
  S += __shfl_xor(S, 32); Q += __shfl_xor(Q, 32);
  __shared__ float ls[4][2*CH];
  int wave = threadIdx.x>>6, wl = threadIdx.x&63;
  if(wl < CH){ ls[wave][wl] = S; ls[wave][CH+wl] = Q; }
  __syncthreads();
  if(threadIdx.x < 2*CH){
    float tsum = ls[0][threadIdx.x]+ls[1][threadIdx.x]+ls[2][threadIdx.x]+ls[3][threadIdx.x];
    part[(size_t)blockIdx.x*16 + threadIdx.x] = tsum;
  }
}

// ---------------- entries: u = xe@W1, v = xe@W2 + hb ----------------
__global__ __launch_bounds__(256) void k_uv(const int* __restrict__ entry, const float* __restrict__ h,
                                            const float* __restrict__ hw, const float* __restrict__ hb,
                                            float* __restrict__ u, float* __restrict__ v){
  __shared__ float w[2*CH*HID];
  __shared__ float b[HID];
  for(int t=threadIdx.x; t<2*CH*HID; t+=256) w[t]=hw[t];
  if(threadIdx.x<HID) b[threadIdx.x]=hb[threadIdx.x];
  __syncthreads();
  int k = blockIdx.x*blockDim.x + threadIdx.x;
  if(k >= NENT) return;
  int node = entry[k];
  const float4* hp = (const float4*)(h + (size_t)node*CH);
  float4 a = hp[0], b4 = hp[1];
  float xe[CH] = {a.x,a.y,a.z,a.w,b4.x,b4.y,b4.z,b4.w};
  #pragma unroll 4
  for(int c=0;c<HID;c++){
    float uu = 0.f, vv = b[c];
    #pragma unroll
    for(int ci=0;ci<CH;ci++){
      uu += xe[ci]*w[ci*HID+c];
      vv += xe[ci]*w[(CH+ci)*HID+c];
    }
    u[(size_t)k*HID+c] = uu;
    v[(size_t)k*HID+c] = vv;
  }
}

// ---------------- pairwise scorer ----------------
__global__ __launch_bounds__(256) void k_pair(const float* __restrict__ u, const float* __restrict__ v,
                                              const float* __restrict__ ow, const float* __restrict__ ob,
                                              float* __restrict__ out){
  __shared__ float us[16][HID+1];
  __shared__ float vs[64][HID+1];
  __shared__ float wo[HID];
  int tid = threadIdx.x;
  int jb = blockIdx.x*64, ib = blockIdx.y*16;
  for(int t=tid; t<16*HID; t+=256) us[t>>5][t&31] = u[(size_t)(ib + (t>>5))*HID + (t&31)];
  for(int t=tid; t<64*HID; t+=256) vs[t>>5][t&31] = v[(size_t)(jb + (t>>5))*HID + (t&31)];
  if(tid<HID) wo[tid]=ow[tid];
  __syncthreads();
  int tx = tid&63, ty = tid>>6;
  float a0=0.f, a1=0.f, a2=0.f, a3=0.f;
  #pragma unroll
  for(int c=0;c<HID;c++){
    float vv = vs[tx][c];
    float w  = wo[c];
    a0 += fmaxf(us[ty   ][c]+vv, 0.f)*w;
    a1 += fmaxf(us[ty+4 ][c]+vv, 0.f)*w;
    a2 += fmaxf(us[ty+8 ][c]+vv, 0.f)*w;
    a3 += fmaxf(us[ty+12][c]+vv, 0.f)*w;
  }
  float o0 = ob[0];
  size_t base = (size_t)ib*2048 + jb + tx;
  out[base + (size_t)(ty   )*2048] = a0+o0;
  out[base + (size_t)(ty+4 )*2048] = a1+o0;
  out[base + (size_t)(ty+8 )*2048] = a2+o0;
  out[base + (size_t)(ty+12)*2048] = a3+o0;
}

extern "C" void kernel_launch(void* const* d_in, const int* in_sizes, int n_in,
                              void* d_out, int out_size, void* d_ws, size_t ws_size,
                              hipStream_t stream){
  const int*   x     = (const int*)d_in[0];
  const int*   ei    = (const int*)d_in[1];
  const int*   entry = (const int*)d_in[2];
  const float* emb   = (const float*)d_in[3];
  const float* gamma = (const float*)d_in[4];
  const float* beta  = (const float*)d_in[5];
  const float* convw = (const float*)d_in[6];
  const float* convb = (const float*)d_in[7];
  const float* hw    = (const float*)d_in[8];
  const float* hb    = (const float*)d_in[9];
  const float* ow    = (const float*)d_in[10];
  const float* ob    = (const float*)d_in[11];
  const int* srcp = ei;
  const int* dstp = ei + NEDGES;

  // workspace (~67 MB)
  char* ws = (char*)d_ws;
  size_t o = 0;
  auto alloc = [&](size_t bytes){ void* p = ws + o; o += (bytes + 255) & ~(size_t)255; return p; };
  int*      cnt    = (int*)     alloc((size_t)NCHUNK*NBUCK*4);   // 2.44 MB
  int*      total  = (int*)     alloc(NBUCK*4);
  int*      bbase  = (int*)     alloc((NBUCK+1)*4);
  unsigned* binned = (unsigned*)alloc((size_t)NEDGES*4);         // 25.6 MB
  int*      csrc   = (int*)     alloc((size_t)NEDGES*4);         // 25.6 MB
  int*      csr_off= (int*)     alloc((NNODES+1)*4);
  float*    dinv   = (float*)   alloc(NNODES*4);
  float*    h      = (float*)   alloc((size_t)NNODES*CH*4);
  __half*   hts16  = (__half*)  alloc((size_t)NNODES*CH*2);      // 3.2 MB (per-XCD L2 resident)
  double*   stats0 = (double*)  alloc(2*CH*8);
  float*    part   = (float*)   alloc((size_t)NPB*16*4);         // 128 KB
  float*    Af     = (float*)   alloc((CH*CH+CH)*4);
  float*    ub     = (float*)   alloc((size_t)NENT*HID*4);
  float*    vb     = (float*)   alloc((size_t)NENT*HID*4);
  (void)ws_size; (void)in_sizes; (void)n_in; (void)out_size;

  // ---- deterministic CSR build (no global atomics) ----
  k_chist<<<NCHUNK, 256, 0, stream>>>(dstp, cnt, NEDGES);
  k_cscan<<<NBUCK, 256, 0, stream>>>(cnt, total);
  k_bscan<<<1, 512, 0, stream>>>(total, bbase);
  k_bin  <<<NCHUNK, 512, 0, stream>>>(srcp, dstp, cnt, bbase, binned, NEDGES);
  k_sub  <<<NBUCK, 512, 0, stream>>>(binned, bbase, csrc, csr_off, dinv, NNODES);

  hipMemsetAsync(stats0, 0, 2*CH*sizeof(double), stream);
  k_init_h<<<(NNODES+255)/256, 256, 0, stream>>>(x, emb, h, stats0, NNODES);

  for(int l=0; l<NCONV; l++){
    k_fold<<<1, 512, 0, stream>>>(stats0, part, (l>0)?1:0, gamma, beta, convw, Af, l);
    k_ht  <<<(NNODES+255)/256, 256, 0, stream>>>(h, Af, dinv, hts16, NNODES);
    k_pull<<<NPB, 256, 0, stream>>>(csr_off, csrc, hts16, dinv, convb, h, part, l, NNODES);
  }

  k_uv<<<NENT/256, 256, 0, stream>>>(entry, h, hw, hb, ub, vb);
  dim3 pg(2048/64, 2048/16);
  k_pair<<<pg, 256, 0, stream>>>(ub, vb, ow, ob, (float*)d_out);
}